// Round 11
// baseline (338.611 us; speedup 1.0000x reference)
//
#include <hip/hip_runtime.h>

#define NN 8192
#define NB2 32
#define NLOW2 528
#define NUP2  496
#define NSPL  36
#define GRIDSZ 1060   // 592 interleaved slots (564 pieces + 28 pad-zfill) + 468 tail zfill

typedef __attribute__((ext_vector_type(8))) __bf16 bf16x8;
typedef __attribute__((ext_vector_type(4))) float f32x4;

// ---------------- compile-time XCD-affinity piece table ----------------
// entry: bj | bi<<5 | kind<<10 | aux<<12   (kind: 0 whole, 1 half0, 2 half1, 3 zfill; aux = pslot or z)
struct Tab { unsigned e[GRIDSZ]; };
constexpr int TRI(int n) { return n * (n + 1) / 2; }
constexpr Tab build_tab() {
  Tab t{};
  // greedy LPT of column work T(32-c) over 8 XCDs
  const int c2x[32] = {0,1,2,3,4,5,6,7, 7,6,5,4,3,2,1,0, 7,6,5,4,3,2,1,0, 2,1,0,3,4,5,3,4};
  unsigned lists[8][80] = {};
  int len[8] = {};
  for (int c = 0; c < 32; ++c) {               // c ascending = work descending
    int x = c2x[c];
    for (int bi = 31; bi >= c; --bi) {         // LPT within column (longest K first)
      int d = bi - c;
      if (d >= 24) {
        int ps = TRI(31 - d) + c;              // matches combine's decode
        lists[x][len[x]++] = (unsigned)(c | (bi << 5) | (1u << 10) | ((unsigned)ps << 12));
        lists[x][len[x]++] = (unsigned)(c | (bi << 5) | (2u << 10) | ((unsigned)ps << 12));
      } else {
        lists[x][len[x]++] = (unsigned)(c | (bi << 5));
      }
    }
  }
  int L = 0;
  for (int x = 0; x < 8; ++x) if (len[x] > L) L = len[x];
  int z = 0, n = 0;
  for (int pos = 0; pos < L; ++pos)
    for (int x = 0; x < 8; ++x) {
      if (pos < len[x]) t.e[n++] = lists[x][pos];
      else             { t.e[n++] = (3u << 10) | ((unsigned)z << 12); ++z; }
    }
  while (z < NUP2 && n < GRIDSZ) { t.e[n++] = (3u << 10) | ((unsigned)z << 12); ++z; }
  return t;
}
static constexpr Tab g_tab = build_tab();

__device__ __forceinline__ void gld_lds16(const void* g, void* l) {
  __builtin_amdgcn_global_load_lds((const __attribute__((address_space(1))) void*)g,
                                   (__attribute__((address_space(3))) void*)l, 16, 0, 0);
}

#define SBAR do { asm volatile("" ::: "memory"); __builtin_amdgcn_s_barrier(); \
                  asm volatile("" ::: "memory"); __builtin_amdgcn_sched_barrier(0); } while(0)
#define WAITVM(N) do { asm volatile("s_waitcnt vmcnt(" #N ")" ::: "memory"); \
                       __builtin_amdgcn_sched_barrier(0); } while(0)

// ---------- fused prep: blocks 0..4095 A-path, 4096..8191 B-path; NT loads of fp32 ----------
__global__ __launch_bounds__(256) void prep(const float* __restrict__ A, const float* __restrict__ B,
                                            __bf16* __restrict__ Ab, __bf16* __restrict__ Bt) {
  __shared__ __bf16 S[128 * 129];
  const int tid = threadIdx.x;
  if (blockIdx.x < 4096) {
    const int r = blockIdx.x;
    const int bi = r >> 6, bk = r & 63;
    if ((bk >> 1) > (bi >> 1)) return;
    const size_t row0 = (size_t)bi * 128, k0 = (size_t)bk * 128;
    #pragma unroll
    for (int i = 0; i < 8; ++i) {
      int u = tid + 256 * i;
      int row = u >> 4, c8 = u & 15;
      size_t grow = row0 + row;
      const f32x4 v0 = __builtin_nontemporal_load((const f32x4*)(A + grow * NN + k0 + c8 * 8));
      const f32x4 v1 = __builtin_nontemporal_load((const f32x4*)(A + grow * NN + k0 + c8 * 8 + 4));
      bf16x8 w;
      #pragma unroll
      for (int c = 0; c < 8; ++c) {
        float f = (c < 4) ? v0[c] : v1[c - 4];
        if (k0 + c8 * 8 + c > grow) f = 0.f;       // tril(A): keep k <= i
        w[c] = (__bf16)f;
      }
      *(bf16x8*)(Ab + grow * NN + k0 + c8 * 8) = w;
    }
  } else {
    const int r = blockIdx.x - 4096;
    const int kb = r >> 6, nb = r & 63;
    if ((kb >> 1) < (nb >> 1)) return;
    const size_t k0 = (size_t)kb * 128, n0 = (size_t)nb * 128;
    #pragma unroll
    for (int i = 0; i < 8; ++i) {
      int u = tid + 256 * i;
      int kr = u >> 4, c8 = u & 15;
      size_t gk = k0 + kr;
      const f32x4 v0 = __builtin_nontemporal_load((const f32x4*)(B + gk * NN + n0 + c8 * 8));
      const f32x4 v1 = __builtin_nontemporal_load((const f32x4*)(B + gk * NN + n0 + c8 * 8 + 4));
      #pragma unroll
      for (int c = 0; c < 8; ++c) {
        float f = (c < 4) ? v0[c] : v1[c - 4];
        int n = c8 * 8 + c;
        if (gk < n0 + n) f = 0.f;                  // tril(B): keep k >= n
        S[n * 129 + kr] = (__bf16)f;
      }
    }
    __syncthreads();
    #pragma unroll
    for (int i = 0; i < 8; ++i) {
      int u = tid + 256 * i;
      int nr = u >> 4, k8 = u & 15;
      bf16x8 w;
      #pragma unroll
      for (int c = 0; c < 8; ++c) w[c] = S[nr * 129 + k8 * 8 + c];
      *(bf16x8*)(Bt + (n0 + nr) * NN + k0 + k8 * 8) = w;
    }
  }
}

// ---------- combine: C tile += partial; 16 blocks per split tile ----------
__global__ __launch_bounds__(256) void combine(const float* __restrict__ P, float* __restrict__ C) {
  const int b = blockIdx.x >> 4, part = blockIdx.x & 15;
  const int tid = threadIdx.x;
  int k = 0;
  while ((k + 1) * (k + 2) / 2 <= b) ++k;
  const int d = 31 - k, bj = b - k * (k + 1) / 2, bi = bj + d;
  const float* p = P + (size_t)b * 65536 + part * 16 * 256;
  float* c = C + (size_t)(bi * 256 + part * 16) * NN + bj * 256;
  #pragma unroll
  for (int i = 0; i < 4; ++i) {
    int u = tid + 256 * i;
    int row = u >> 6, c4 = u & 63;
    f32x4 cv = *(f32x4*)(c + (size_t)row * NN + c4 * 4);
    const f32x4 pv = __builtin_nontemporal_load((const f32x4*)(p + row * 256 + c4 * 4));
    cv += pv;
    *(f32x4*)(c + (size_t)row * NN + c4 * 4) = cv;
  }
}

// ---------- main: 256x256 tile, BK=64, 8 waves, 8-phase pipeline, 16x16x32 MFMA ----------
__global__ __launch_bounds__(512, 2) void trimm(const __bf16* __restrict__ Ab,
                                                const __bf16* __restrict__ Bt,
                                                float* __restrict__ C,
                                                float* __restrict__ P,
                                                const int mode) {
  int p = blockIdx.x;
  const int tid = threadIdx.x;

  // ---- piece decode ----
  int bi, bj, dd, nkt, k_lo;
  bool diag = false, topart = false;
  int pslot = 0;
  int zfill = -1;
  if (mode == 1) {                                 // XCD-affinity table
    const unsigned e = g_tab.e[p];
    const int kind = (e >> 10) & 3;
    if (kind == 3) {
      zfill = (int)(e >> 12);
    } else {
      bj = e & 31; bi = (e >> 5) & 31; dd = bi - bj;
      if (kind == 0) { nkt = (dd + 1) * 4; k_lo = bj * 256; diag = (dd == 0); }
      else {
        nkt = (dd + 1) * 2;
        k_lo = bj * 256 + ((kind == 2) ? nkt * 64 : 0);
        topart = (kind == 2); pslot = (int)((e >> 12) & 63);
      }
    }
  } else {                                         // plain fallback (no split, no P)
    if (p < NLOW2) {
      dd = NB2 - 1; int u = p;
      while (u >= NB2 - dd) { u -= NB2 - dd; --dd; }
      bj = u; bi = u + dd; nkt = (dd + 1) * 4; k_lo = bj * 256;
      diag = (dd == 0);
    } else zfill = p - NLOW2;
  }

  if (zfill >= 0) {                                // strict-upper zero-fill
    int u = zfill;
    int bi0 = 0;
    while (u >= NB2 - 1 - bi0) { u -= NB2 - 1 - bi0; ++bi0; }
    int bj0 = bi0 + 1 + u;
    const size_t base = (size_t)bi0 * 256 * NN + (size_t)bj0 * 256;
    const f32x4 z = (f32x4){0.f, 0.f, 0.f, 0.f};
    #pragma unroll
    for (int i = 0; i < 32; ++i) {
      int f = tid + 512 * i;
      int row = f >> 6, c4 = f & 63;
      *(f32x4*)(C + base + (size_t)row * NN + c4 * 4) = z;
    }
    return;
  }

  __shared__ __align__(16) char lds[131072];

  const int lane = tid & 63;
  const int wid  = tid >> 6;
  const int wr = wid >> 2, wc = wid & 3;
  const int lrow = lane & 15;
  const int kgrp = lane >> 4;
  const int tid16 = tid * 16;

  const int arow0 = bi * 256, bcol0 = bj * 256;
  const int niter = nkt >> 1;

  const int tA = tid & 255;
  const int uA = tA >> 3, slA = tA & 7;
  const int cA = slA ^ (uA & 7);
  const int rowA = 2 * uA + (cA >> 2);
  const int kcA = cA & 3;
  const int kkA = tid >> 8;
  const __bf16* aSrcA = Ab + (size_t)(arow0 + rowA) * NN + kkA * 32 + kcA * 8;
  const int uB = tid >> 3, slB = tid & 7;
  const int cB = slB ^ (uB & 7);
  const int rowB = 2 * uB + (cB >> 2);
  const int kcB = cB & 3;
  const __bf16* bSrcB = Bt + (size_t)(bcol0 + rowB) * NN + kcB * 8;

  const int rdoff = (lrow >> 1) * 128 + (((((lrow & 1) << 2) | kgrp)) ^ (lrow >> 1)) * 16;
  const int bhalf = wc >> 1;

  f32x4 acc[8][4];
  #pragma unroll
  for (int m = 0; m < 8; ++m)
    #pragma unroll
    for (int n = 0; n < 4; ++n) acc[m][n] = (f32x4){0.f, 0.f, 0.f, 0.f};

  gld_lds16(aSrcA + k_lo,                          lds + tid16);
  gld_lds16(aSrcA + k_lo + (size_t)128 * NN,       lds + 16384 + tid16);
  gld_lds16(aSrcA + k_lo + (size_t)64 * NN,        lds + 8192 + tid16);
  gld_lds16(aSrcA + k_lo + (size_t)192 * NN,       lds + 16384 + 8192 + tid16);
  gld_lds16(bSrcB + k_lo,                          lds + 32768 + tid16);
  gld_lds16(bSrcB + k_lo + 32,                     lds + 32768 + 8192 + tid16);
  gld_lds16(bSrcB + k_lo + (size_t)128 * NN,       lds + 32768 + 16384 + tid16);
  gld_lds16(bSrcB + k_lo + (size_t)128 * NN + 32,  lds + 32768 + 16384 + 8192 + tid16);
  gld_lds16(bSrcB + k_lo + 64,                     lds + 65536 + 32768 + tid16);
  gld_lds16(bSrcB + k_lo + 64 + 32,                lds + 65536 + 32768 + 8192 + tid16);
  gld_lds16(aSrcA + k_lo + 64,                     lds + 65536 + tid16);
  gld_lds16(aSrcA + k_lo + 64 + (size_t)128 * NN,  lds + 65536 + 16384 + tid16);
  gld_lds16(bSrcB + k_lo + 64 + (size_t)128 * NN,      lds + 65536 + 32768 + 16384 + tid16);
  gld_lds16(bSrcB + k_lo + 64 + (size_t)128 * NN + 32, lds + 65536 + 32768 + 16384 + 8192 + tid16);
  WAITVM(6);
  SBAR;

#define QUAD(TT, PP) do {                                                                  \
    const int t_ = (TT);                                                                   \
    bf16x8 b_[4][2];                                                                       \
    _Pragma("unroll")                                                                      \
    for (int q = 0; q < 4; ++q) {                                                          \
      bf16x8 a_[2][2];                                                                     \
      if (q == 0) {                                                                        \
        _Pragma("unroll")                                                                  \
        for (int n = 0; n < 4; ++n)                                                        \
          _Pragma("unroll")                                                                \
          for (int kk = 0; kk < 2; ++kk)                                                   \
            b_[n][kk] = *(const bf16x8*)(lds + (PP)*65536 + 32768 + bhalf*16384            \
                                         + kk*8192 + ((wc & 1)*4 + n)*1024 + rdoff);       \
      }                                                                                    \
      _Pragma("unroll")                                                                    \
      for (int j = 0; j < 2; ++j)                                                          \
        _Pragma("unroll")                                                                  \
        for (int kk = 0; kk < 2; ++kk) {                                                   \
          const int m_ = 2*q + j;                                                          \
          a_[j][kk] = *(const bf16x8*)(lds + (PP)*65536 + wr*16384 + (m_>>2)*8192          \
                                       + kk*4096 + (m_&3)*1024 + rdoff);                   \
        }                                                                                  \
      if (q == 0) { if (t_ + 1 < nkt) {                                                    \
        const __bf16* s0 = aSrcA + (size_t)64*NN + (k_lo + (t_+1)*64);                     \
        gld_lds16(s0,                      lds + ((PP)^1)*65536 + 8192 + tid16);           \
        gld_lds16(s0 + (size_t)128*NN,     lds + ((PP)^1)*65536 + 16384 + 8192 + tid16); } \
      } else if (q == 1) { if (t_ + 2 < nkt) {                                             \
        const __bf16* s0 = bSrcB + (k_lo + (t_+2)*64);                                     \
        gld_lds16(s0,                      lds + (PP)*65536 + 32768 + tid16);              \
        gld_lds16(s0 + 32,                 lds + (PP)*65536 + 32768 + 8192 + tid16); }     \
      } else if (q == 2) { if (t_ + 2 < nkt) {                                             \
        const __bf16* s0 = aSrcA + (k_lo + (t_+2)*64);                                     \
        gld_lds16(s0,                      lds + (PP)*65536 + tid16);                      \
        gld_lds16(s0 + (size_t)128*NN,     lds + (PP)*65536 + 16384 + tid16); }            \
      } else { if (t_ + 2 < nkt) {                                                         \
        const __bf16* s0 = bSrcB + (size_t)128*NN + (k_lo + (t_+2)*64);                    \
        gld_lds16(s0,                      lds + (PP)*65536 + 32768 + 16384 + tid16);      \
        gld_lds16(s0 + 32,                 lds + (PP)*65536 + 32768 + 16384 + 8192 + tid16); } \
      }                                                                                    \
      SBAR;                                                                                \
      __builtin_amdgcn_s_setprio(1);                                                       \
      _Pragma("unroll")                                                                    \
      for (int j = 0; j < 2; ++j)                                                          \
        _Pragma("unroll")                                                                  \
        for (int n = 0; n < 4; ++n)                                                        \
          _Pragma("unroll")                                                                \
          for (int kk = 0; kk < 2; ++kk)                                                   \
            acc[2*q+j][n] = __builtin_amdgcn_mfma_f32_16x16x32_bf16(                       \
                a_[j][kk], b_[n][kk], acc[2*q+j][n], 0, 0, 0);                             \
      __builtin_amdgcn_s_setprio(0);                                                       \
      if (q == 3) { if (t_ + 2 < nkt) { WAITVM(6); } else { WAITVM(0); } }                 \
      SBAR;                                                                                \
    }                                                                                      \
  } while (0)

  for (int it = 0; it < niter; ++it) {
    QUAD(2 * it, 0);
    QUAD(2 * it + 1, 1);
  }
#undef QUAD

  float* outp;
  size_t ostride;
  if (topart) { outp = P + (size_t)pslot * 65536; ostride = 256; }
  else        { outp = C + (size_t)arow0 * NN + bcol0; ostride = NN; }
  #pragma unroll
  for (int m = 0; m < 8; ++m) {
    #pragma unroll
    for (int n = 0; n < 4; ++n) {
      #pragma unroll
      for (int qq = 0; qq < 4; ++qq) {
        int rloc = wr * 128 + m * 16 + kgrp * 4 + qq;
        int cloc = wc * 64 + n * 16 + lrow;
        float v = acc[m][n][qq];
        if (diag && cloc > rloc) v = 0.f;
        outp[(size_t)rloc * ostride + cloc] = v;
      }
    }
  }
}

extern "C" void kernel_launch(void* const* d_in, const int* in_sizes, int n_in,
                              void* d_out, int out_size, void* d_ws, size_t ws_size,
                              hipStream_t stream) {
  const float* A = (const float*)d_in[0];
  const float* B = (const float*)d_in[1];
  float* C = (float*)d_out;
  (void)in_sizes; (void)n_in; (void)out_size;

  const size_t needBase = (size_t)NN * NN * sizeof(__bf16) * 2;                 // 256 MB
  const size_t need1 = needBase + (size_t)NSPL * 65536 * sizeof(float);         // +9.4 MB
  __bf16* Ab = (__bf16*)d_ws;
  __bf16* Bt = Ab + (size_t)NN * NN;
  float*  P  = (float*)((char*)d_ws + needBase);

  hipLaunchKernelGGL(prep, dim3(8192), dim3(256), 0, stream, A, B, Ab, Bt);
  if (ws_size >= need1) {
    hipLaunchKernelGGL(trimm, dim3(GRIDSZ), dim3(512), 0, stream, Ab, Bt, C, P, 1);
    hipLaunchKernelGGL(combine, dim3(NSPL * 16), dim3(256), 0, stream, P, C);
  } else {
    hipLaunchKernelGGL(trimm, dim3(NLOW2 + NUP2), dim3(512), 0, stream, Ab, Bt, C, P, 0);
  }
}

// Round 12
// 309.517 us; speedup vs baseline: 1.0940x; 1.0940x over previous
//
#include <hip/hip_runtime.h>

#define NN 8192
#define NB2 32
#define NLOW2 528
// mode 1 segments: [84 whole d=23..17][72 split-halves d>=24][408 whole d=16..0][496 zfill]
#define M1_SEGA 84
#define M1_SEGB 72
#define M1_NPC  564
#define M1_NSPL 36
#define NUP2  496

typedef __attribute__((ext_vector_type(8))) __bf16 bf16x8;
typedef __attribute__((ext_vector_type(4))) float f32x4;

__device__ __forceinline__ void gld_lds16(const void* g, void* l) {
  __builtin_amdgcn_global_load_lds((const __attribute__((address_space(1))) void*)g,
                                   (__attribute__((address_space(3))) void*)l, 16, 0, 0);
}

#define SBAR do { asm volatile("" ::: "memory"); __builtin_amdgcn_s_barrier(); \
                  asm volatile("" ::: "memory"); __builtin_amdgcn_sched_barrier(0); } while(0)
#define WAITVM(N) do { asm volatile("s_waitcnt vmcnt(" #N ")" ::: "memory"); \
                       __builtin_amdgcn_sched_barrier(0); } while(0)

// ---------- fused prep: blocks 0..4095 A-path, 4096..8191 B-path; NT loads of fp32 ----------
__global__ __launch_bounds__(256) void prep(const float* __restrict__ A, const float* __restrict__ B,
                                            __bf16* __restrict__ Ab, __bf16* __restrict__ Bt) {
  __shared__ __bf16 S[128 * 129];
  const int tid = threadIdx.x;
  if (blockIdx.x < 4096) {
    const int r = blockIdx.x;
    const int bi = r >> 6, bk = r & 63;
    if ((bk >> 1) > (bi >> 1)) return;
    const size_t row0 = (size_t)bi * 128, k0 = (size_t)bk * 128;
    #pragma unroll
    for (int i = 0; i < 8; ++i) {
      int u = tid + 256 * i;
      int row = u >> 4, c8 = u & 15;
      size_t grow = row0 + row;
      const f32x4 v0 = __builtin_nontemporal_load((const f32x4*)(A + grow * NN + k0 + c8 * 8));
      const f32x4 v1 = __builtin_nontemporal_load((const f32x4*)(A + grow * NN + k0 + c8 * 8 + 4));
      bf16x8 w;
      #pragma unroll
      for (int c = 0; c < 8; ++c) {
        float f = (c < 4) ? v0[c] : v1[c - 4];
        if (k0 + c8 * 8 + c > grow) f = 0.f;       // tril(A): keep k <= i
        w[c] = (__bf16)f;
      }
      *(bf16x8*)(Ab + grow * NN + k0 + c8 * 8) = w;
    }
  } else {
    const int r = blockIdx.x - 4096;
    const int kb = r >> 6, nb = r & 63;
    if ((kb >> 1) < (nb >> 1)) return;
    const size_t k0 = (size_t)kb * 128, n0 = (size_t)nb * 128;
    #pragma unroll
    for (int i = 0; i < 8; ++i) {
      int u = tid + 256 * i;
      int kr = u >> 4, c8 = u & 15;
      size_t gk = k0 + kr;
      const f32x4 v0 = __builtin_nontemporal_load((const f32x4*)(B + gk * NN + n0 + c8 * 8));
      const f32x4 v1 = __builtin_nontemporal_load((const f32x4*)(B + gk * NN + n0 + c8 * 8 + 4));
      #pragma unroll
      for (int c = 0; c < 8; ++c) {
        float f = (c < 4) ? v0[c] : v1[c - 4];
        int n = c8 * 8 + c;
        if (gk < n0 + n) f = 0.f;                  // tril(B): keep k >= n
        S[n * 129 + kr] = (__bf16)f;
      }
    }
    __syncthreads();
    #pragma unroll
    for (int i = 0; i < 8; ++i) {
      int u = tid + 256 * i;
      int nr = u >> 4, k8 = u & 15;
      bf16x8 w;
      #pragma unroll
      for (int c = 0; c < 8; ++c) w[c] = S[nr * 129 + k8 * 8 + c];
      *(bf16x8*)(Bt + (n0 + nr) * NN + k0 + k8 * 8) = w;
    }
  }
}

// ---------- combine: C tile += partial; 16 blocks per split tile ----------
__global__ __launch_bounds__(256) void combine(const float* __restrict__ P, float* __restrict__ C) {
  const int b = blockIdx.x >> 4, part = blockIdx.x & 15;
  const int tid = threadIdx.x;
  int k = 0;
  while ((k + 1) * (k + 2) / 2 <= b) ++k;
  const int d = 31 - k, bj = b - k * (k + 1) / 2, bi = bj + d;
  const float* p = P + (size_t)b * 65536 + part * 16 * 256;
  float* c = C + (size_t)(bi * 256 + part * 16) * NN + bj * 256;
  #pragma unroll
  for (int i = 0; i < 4; ++i) {
    int u = tid + 256 * i;
    int row = u >> 6, c4 = u & 63;
    f32x4 cv = *(f32x4*)(c + (size_t)row * NN + c4 * 4);
    const f32x4 pv = __builtin_nontemporal_load((const f32x4*)(p + row * 256 + c4 * 4));
    cv += pv;
    *(f32x4*)(c + (size_t)row * NN + c4 * 4) = cv;
  }
}

// ---------- main: 256x256 tile, BK=64, 8 waves, 8-phase pipeline, 16x16x32 MFMA (R6-proven) ----------
__global__ __launch_bounds__(512, 2) void trimm(const __bf16* __restrict__ Ab,
                                                const __bf16* __restrict__ Bt,
                                                float* __restrict__ C,
                                                float* __restrict__ P,
                                                const int mode) {
  int p = blockIdx.x;
  const int tid = threadIdx.x;

  // ---- piece decode (mode 1 = global heavy-first LPT with 36 split tiles; mode 0 = plain) ----
  int bi, bj, dd, nkt, k_lo;
  bool diag = false, topart = false;
  int pslot = 0;
  int zfill = -1;
  if (mode == 1) {
    if (p < M1_SEGA) {                             // whole d=23..17
      dd = 23; int u = p;
      while (u >= NB2 - dd) { u -= NB2 - dd; --dd; }
      bj = u; bi = u + dd; nkt = (dd + 1) * 4; k_lo = bj * 256;
    } else if (p < M1_SEGA + M1_SEGB) {            // split halves d=31..24
      int q = p - M1_SEGA;
      int b = q >> 1, half = q & 1;
      int k = 0;
      while ((k + 1) * (k + 2) / 2 <= b) ++k;
      dd = 31 - k; bj = b - k * (k + 1) / 2; bi = bj + dd;
      nkt = (dd + 1) * 2;
      k_lo = bj * 256 + half * nkt * 64;
      topart = (half == 1); pslot = b;
    } else if (p < M1_NPC) {                       // whole d=16..0
      int u = p - (M1_SEGA + M1_SEGB);
      dd = 16;
      while (u >= NB2 - dd) { u -= NB2 - dd; --dd; }
      bj = u; bi = u + dd; nkt = (dd + 1) * 4; k_lo = bj * 256;
      diag = (dd == 0);
    } else zfill = p - M1_NPC;
  } else {
    if (p < NLOW2) {
      dd = NB2 - 1; int u = p;
      while (u >= NB2 - dd) { u -= NB2 - dd; --dd; }
      bj = u; bi = u + dd; nkt = (dd + 1) * 4; k_lo = bj * 256;
      diag = (dd == 0);
    } else zfill = p - NLOW2;
  }

  if (zfill >= 0) {                                // strict-upper zero-fill (tail)
    int u = zfill;
    int bi0 = 0;
    while (u >= NB2 - 1 - bi0) { u -= NB2 - 1 - bi0; ++bi0; }
    int bj0 = bi0 + 1 + u;
    const size_t base = (size_t)bi0 * 256 * NN + (size_t)bj0 * 256;
    const f32x4 z = (f32x4){0.f, 0.f, 0.f, 0.f};
    #pragma unroll
    for (int i = 0; i < 32; ++i) {
      int f = tid + 512 * i;
      int row = f >> 6, c4 = f & 63;
      *(f32x4*)(C + base + (size_t)row * NN + c4 * 4) = z;
    }
    return;
  }

  __shared__ __align__(16) char lds[131072];

  const int lane = tid & 63;
  const int wid  = tid >> 6;
  const int wr = wid >> 2, wc = wid & 3;
  const int lrow = lane & 15;
  const int kgrp = lane >> 4;
  const int tid16 = tid * 16;

  const int arow0 = bi * 256, bcol0 = bj * 256;
  const int niter = nkt >> 1;

  const int tA = tid & 255;
  const int uA = tA >> 3, slA = tA & 7;
  const int cA = slA ^ (uA & 7);
  const int rowA = 2 * uA + (cA >> 2);
  const int kcA = cA & 3;
  const int kkA = tid >> 8;
  const __bf16* aSrcA = Ab + (size_t)(arow0 + rowA) * NN + kkA * 32 + kcA * 8;
  const int uB = tid >> 3, slB = tid & 7;
  const int cB = slB ^ (uB & 7);
  const int rowB = 2 * uB + (cB >> 2);
  const int kcB = cB & 3;
  const __bf16* bSrcB = Bt + (size_t)(bcol0 + rowB) * NN + kcB * 8;

  const int rdoff = (lrow >> 1) * 128 + (((((lrow & 1) << 2) | kgrp)) ^ (lrow >> 1)) * 16;
  const int bhalf = wc >> 1;

  f32x4 acc[8][4];
  #pragma unroll
  for (int m = 0; m < 8; ++m)
    #pragma unroll
    for (int n = 0; n < 4; ++n) acc[m][n] = (f32x4){0.f, 0.f, 0.f, 0.f};

  gld_lds16(aSrcA + k_lo,                          lds + tid16);
  gld_lds16(aSrcA + k_lo + (size_t)128 * NN,       lds + 16384 + tid16);
  gld_lds16(aSrcA + k_lo + (size_t)64 * NN,        lds + 8192 + tid16);
  gld_lds16(aSrcA + k_lo + (size_t)192 * NN,       lds + 16384 + 8192 + tid16);
  gld_lds16(bSrcB + k_lo,                          lds + 32768 + tid16);
  gld_lds16(bSrcB + k_lo + 32,                     lds + 32768 + 8192 + tid16);
  gld_lds16(bSrcB + k_lo + (size_t)128 * NN,       lds + 32768 + 16384 + tid16);
  gld_lds16(bSrcB + k_lo + (size_t)128 * NN + 32,  lds + 32768 + 16384 + 8192 + tid16);
  gld_lds16(bSrcB + k_lo + 64,                     lds + 65536 + 32768 + tid16);
  gld_lds16(bSrcB + k_lo + 64 + 32,                lds + 65536 + 32768 + 8192 + tid16);
  gld_lds16(aSrcA + k_lo + 64,                     lds + 65536 + tid16);
  gld_lds16(aSrcA + k_lo + 64 + (size_t)128 * NN,  lds + 65536 + 16384 + tid16);
  gld_lds16(bSrcB + k_lo + 64 + (size_t)128 * NN,      lds + 65536 + 32768 + 16384 + tid16);
  gld_lds16(bSrcB + k_lo + 64 + (size_t)128 * NN + 32, lds + 65536 + 32768 + 16384 + 8192 + tid16);
  WAITVM(6);
  SBAR;

#define QUAD(TT, PP) do {                                                                  \
    const int t_ = (TT);                                                                   \
    bf16x8 b_[4][2];                                                                       \
    _Pragma("unroll")                                                                      \
    for (int q = 0; q < 4; ++q) {                                                          \
      bf16x8 a_[2][2];                                                                     \
      if (q == 0) {                                                                        \
        _Pragma("unroll")                                                                  \
        for (int n = 0; n < 4; ++n)                                                        \
          _Pragma("unroll")                                                                \
          for (int kk = 0; kk < 2; ++kk)                                                   \
            b_[n][kk] = *(const bf16x8*)(lds + (PP)*65536 + 32768 + bhalf*16384            \
                                         + kk*8192 + ((wc & 1)*4 + n)*1024 + rdoff);       \
      }                                                                                    \
      _Pragma("unroll")                                                                    \
      for (int j = 0; j < 2; ++j)                                                          \
        _Pragma("unroll")                                                                  \
        for (int kk = 0; kk < 2; ++kk) {                                                   \
          const int m_ = 2*q + j;                                                          \
          a_[j][kk] = *(const bf16x8*)(lds + (PP)*65536 + wr*16384 + (m_>>2)*8192          \
                                       + kk*4096 + (m_&3)*1024 + rdoff);                   \
        }                                                                                  \
      if (q == 0) { if (t_ + 1 < nkt) {                                                    \
        const __bf16* s0 = aSrcA + (size_t)64*NN + (k_lo + (t_+1)*64);                     \
        gld_lds16(s0,                      lds + ((PP)^1)*65536 + 8192 + tid16);           \
        gld_lds16(s0 + (size_t)128*NN,     lds + ((PP)^1)*65536 + 16384 + 8192 + tid16); } \
      } else if (q == 1) { if (t_ + 2 < nkt) {                                             \
        const __bf16* s0 = bSrcB + (k_lo + (t_+2)*64);                                     \
        gld_lds16(s0,                      lds + (PP)*65536 + 32768 + tid16);              \
        gld_lds16(s0 + 32,                 lds + (PP)*65536 + 32768 + 8192 + tid16); }     \
      } else if (q == 2) { if (t_ + 2 < nkt) {                                             \
        const __bf16* s0 = aSrcA + (k_lo + (t_+2)*64);                                     \
        gld_lds16(s0,                      lds + (PP)*65536 + tid16);                      \
        gld_lds16(s0 + (size_t)128*NN,     lds + (PP)*65536 + 16384 + tid16); }            \
      } else { if (t_ + 2 < nkt) {                                                         \
        const __bf16* s0 = bSrcB + (size_t)128*NN + (k_lo + (t_+2)*64);                    \
        gld_lds16(s0,                      lds + (PP)*65536 + 32768 + 16384 + tid16);      \
        gld_lds16(s0 + 32,                 lds + (PP)*65536 + 32768 + 16384 + 8192 + tid16); } \
      }                                                                                    \
      SBAR;                                                                                \
      __builtin_amdgcn_s_setprio(1);                                                       \
      _Pragma("unroll")                                                                    \
      for (int j = 0; j < 2; ++j)                                                          \
        _Pragma("unroll")                                                                  \
        for (int n = 0; n < 4; ++n)                                                        \
          _Pragma("unroll")                                                                \
          for (int kk = 0; kk < 2; ++kk)                                                   \
            acc[2*q+j][n] = __builtin_amdgcn_mfma_f32_16x16x32_bf16(                       \
                a_[j][kk], b_[n][kk], acc[2*q+j][n], 0, 0, 0);                             \
      __builtin_amdgcn_s_setprio(0);                                                       \
      if (q == 3) { if (t_ + 2 < nkt) { WAITVM(6); } else { WAITVM(0); } }                 \
      SBAR;                                                                                \
    }                                                                                      \
  } while (0)

  for (int it = 0; it < niter; ++it) {
    QUAD(2 * it, 0);
    QUAD(2 * it + 1, 1);
  }
#undef QUAD

  float* outp;
  size_t ostride;
  if (topart) { outp = P + (size_t)pslot * 65536; ostride = 256; }
  else        { outp = C + (size_t)arow0 * NN + bcol0; ostride = NN; }
  #pragma unroll
  for (int m = 0; m < 8; ++m) {
    #pragma unroll
    for (int n = 0; n < 4; ++n) {
      #pragma unroll
      for (int qq = 0; qq < 4; ++qq) {
        int rloc = wr * 128 + m * 16 + kgrp * 4 + qq;
        int cloc = wc * 64 + n * 16 + lrow;
        float v = acc[m][n][qq];
        if (diag && cloc > rloc) v = 0.f;
        outp[(size_t)rloc * ostride + cloc] = v;
      }
    }
  }
}

extern "C" void kernel_launch(void* const* d_in, const int* in_sizes, int n_in,
                              void* d_out, int out_size, void* d_ws, size_t ws_size,
                              hipStream_t stream) {
  const float* A = (const float*)d_in[0];
  const float* B = (const float*)d_in[1];
  float* C = (float*)d_out;
  (void)in_sizes; (void)n_in; (void)out_size;

  const size_t needBase = (size_t)NN * NN * sizeof(__bf16) * 2;                 // 256 MB
  const size_t need1 = needBase + (size_t)M1_NSPL * 65536 * sizeof(float);      // +9.4 MB
  __bf16* Ab = (__bf16*)d_ws;
  __bf16* Bt = Ab + (size_t)NN * NN;
  float*  P  = (float*)((char*)d_ws + needBase);

  hipLaunchKernelGGL(prep, dim3(8192), dim3(256), 0, stream, A, B, Ab, Bt);
  if (ws_size >= need1) {
    hipLaunchKernelGGL(trimm, dim3(M1_NPC + NUP2), dim3(512), 0, stream, Ab, Bt, C, P, 1);
    hipLaunchKernelGGL(combine, dim3(M1_NSPL * 16), dim3(256), 0, stream, P, C);
  } else {
    hipLaunchKernelGGL(trimm, dim3(NLOW2 + NUP2), dim3(512), 0, stream, Ab, Bt, C, P, 0);
  }
}